// Round 1
// baseline (1256.012 us; speedup 1.0000x reference)
//
#include <hip/hip_runtime.h>

#define NUM_USERS 50000
#define NUM_ITEMS 100000
#define NUM_NODES 150000   // NUM_USERS + NUM_ITEMS
#define D 64
#define NNZ 4800000
#define BATCH 4096
// light_out = acc / (N_LAYERS+1) = acc/4 ; gamma = (acc_u/4)·(acc_i/4) = dot/16

// ---------------------------------------------------------------------------
// k_init: cur = acc = concat(user_emb, item_emb), vectorized float4
// ---------------------------------------------------------------------------
__global__ void k_init(const float* __restrict__ ue, const float* __restrict__ ie,
                       float* __restrict__ cur, float* __restrict__ acc) {
    const int total = NUM_NODES * D / 4;     // 2.4M float4
    const int ulim  = NUM_USERS * D / 4;
    const float4* u4 = (const float4*)ue;
    const float4* i4 = (const float4*)ie;
    float4* c4 = (float4*)cur;
    float4* a4 = (float4*)acc;
    for (int i = blockIdx.x * blockDim.x + threadIdx.x; i < total;
         i += gridDim.x * blockDim.x) {
        float4 v = (i < ulim) ? u4[i] : i4[i - ulim];
        c4[i] = v;
        a4[i] = v;
    }
}

// ---------------------------------------------------------------------------
// k_rowptr: rowptr[r] = lower_bound(rows, r)  (rows is sorted)
// ---------------------------------------------------------------------------
__global__ void k_rowptr(const int* __restrict__ rows, int* __restrict__ rowptr) {
    int r = blockIdx.x * blockDim.x + threadIdx.x;
    if (r > NUM_NODES) return;
    int lo = 0, hi = NNZ;
    while (lo < hi) {
        int mid = (lo + hi) >> 1;
        if (rows[mid] < r) lo = mid + 1; else hi = mid;
    }
    rowptr[r] = lo;
}

// ---------------------------------------------------------------------------
// k_spmm: one wave per row, lane = feature dim.
//   sum_lane = sum_e vals[e] * x[cols[e]*64 + lane]
//   nxt[row] = sum  (skipped on last layer) ; acc[row] += sum  (fused)
// No atomics: each row owned by exactly one wave. Deterministic order.
// ---------------------------------------------------------------------------
template <bool WRITE_NEXT>
__global__ void k_spmm(const int* __restrict__ rowptr,
                       const int* __restrict__ cols,
                       const float* __restrict__ vals,
                       const float* __restrict__ x,
                       float* __restrict__ nxt,
                       float* __restrict__ acc) {
    int wid  = (blockIdx.x * blockDim.x + threadIdx.x) >> 6;
    int lane = threadIdx.x & 63;
    if (wid >= NUM_NODES) return;
    int e0 = rowptr[wid];
    int e1 = rowptr[wid + 1];
    float sum = 0.f;
    for (int e = e0; e < e1; ++e) {
        int   c = cols[e];   // wave-uniform address, HW broadcasts
        float v = vals[e];
        sum += v * x[(size_t)c * D + lane];   // coalesced 256B gather per edge
    }
    size_t o = (size_t)wid * D + lane;
    if (WRITE_NEXT) nxt[o] = sum;
    acc[o] += sum;
}

// ---------------------------------------------------------------------------
// k_gamma: one wave per batch element; 64-lane dot + shuffle reduce; /16
// ---------------------------------------------------------------------------
__global__ void k_gamma(const float* __restrict__ acc,
                        const int* __restrict__ users,
                        const int* __restrict__ items,
                        float* __restrict__ out) {
    int wid  = (blockIdx.x * blockDim.x + threadIdx.x) >> 6;
    int lane = threadIdx.x & 63;
    if (wid >= BATCH) return;
    int u  = users[wid];
    int it = items[wid];
    float a = acc[(size_t)u * D + lane];
    float b = acc[((size_t)NUM_USERS + it) * D + lane];
    float p = a * b;
    for (int off = 32; off; off >>= 1) p += __shfl_down(p, off);
    if (lane == 0) out[wid] = p * (1.0f / 16.0f);
}

extern "C" void kernel_launch(void* const* d_in, const int* in_sizes, int n_in,
                              void* d_out, int out_size, void* d_ws, size_t ws_size,
                              hipStream_t stream) {
    const float* ue    = (const float*)d_in[0];
    const float* ie    = (const float*)d_in[1];
    const int*   rows  = (const int*)d_in[2];
    const int*   cols  = (const int*)d_in[3];
    const float* vals  = (const float*)d_in[4];
    const int*   users = (const int*)d_in[5];
    const int*   items = (const int*)d_in[6];
    float*       out   = (float*)d_out;

    // workspace layout: rowptr | bufA | bufB | acc
    char* ws = (char*)d_ws;
    size_t off = (((size_t)(NUM_NODES + 1) * sizeof(int)) + 255) & ~(size_t)255;
    int*   rowptr = (int*)ws;
    float* bufA   = (float*)(ws + off);
    float* bufB   = (float*)(ws + off + 1ull * NUM_NODES * D * sizeof(float));
    float* acc    = (float*)(ws + off + 2ull * NUM_NODES * D * sizeof(float));

    // rowptr build: 150001 binary searches
    k_rowptr<<<(NUM_NODES + 1 + 255) / 256, 256, 0, stream>>>(rows, rowptr);

    // init cur & acc
    k_init<<<2048, 256, 0, stream>>>(ue, ie, bufA, acc);

    // 3 SpMM layers, acc fused; ping-pong bufA/bufB; last layer acc-only
    const int spmm_blocks = (NUM_NODES + 3) / 4;   // 4 waves (rows) per 256-thr block
    k_spmm<true ><<<spmm_blocks, 256, 0, stream>>>(rowptr, cols, vals, bufA, bufB, acc);
    k_spmm<true ><<<spmm_blocks, 256, 0, stream>>>(rowptr, cols, vals, bufB, bufA, acc);
    k_spmm<false><<<spmm_blocks, 256, 0, stream>>>(rowptr, cols, vals, bufA, nullptr, acc);

    // gamma: 4096 waves
    k_gamma<<<(BATCH * 64) / 256, 256, 0, stream>>>(acc, users, items, out);
}

// Round 2
// 581.567 us; speedup vs baseline: 2.1597x; 2.1597x over previous
//
#include <hip/hip_runtime.h>

#define NUM_USERS 50000
#define NUM_ITEMS 100000
#define NUM_NODES 150000   // NUM_USERS + NUM_ITEMS
#define D 64
#define NNZ 4800000
#define BATCH 4096
// light_out = acc / (N_LAYERS+1) = acc/4 ; gamma = (acc_u/4)·(acc_i/4) = dot/16

// ---------------------------------------------------------------------------
// k_init: cur = acc = concat(user_emb, item_emb), vectorized float4
// ---------------------------------------------------------------------------
__global__ void k_init(const float* __restrict__ ue, const float* __restrict__ ie,
                       float* __restrict__ cur, float* __restrict__ acc) {
    const int total = NUM_NODES * D / 4;     // 2.4M float4
    const int ulim  = NUM_USERS * D / 4;
    const float4* u4 = (const float4*)ue;
    const float4* i4 = (const float4*)ie;
    float4* c4 = (float4*)cur;
    float4* a4 = (float4*)acc;
    for (int i = blockIdx.x * blockDim.x + threadIdx.x; i < total;
         i += gridDim.x * blockDim.x) {
        float4 v = (i < ulim) ? u4[i] : i4[i - ulim];
        c4[i] = v;
        a4[i] = v;
    }
}

// ---------------------------------------------------------------------------
// k_rowptr: rowptr[r] = lower_bound(rows, r)  (rows is sorted)
// ---------------------------------------------------------------------------
__global__ void k_rowptr(const int* __restrict__ rows, int* __restrict__ rowptr) {
    int r = blockIdx.x * blockDim.x + threadIdx.x;
    if (r > NUM_NODES) return;
    int lo = 0, hi = NNZ;
    while (lo < hi) {
        int mid = (lo + hi) >> 1;
        if (rows[mid] < r) lo = mid + 1; else hi = mid;
    }
    rowptr[r] = lo;
}

// ---------------------------------------------------------------------------
// k_spmm: 16 lanes per row (float4 per lane), 4 rows per wave.
// Metadata staged cooperatively: 16 lanes load 16 edges' cols/vals in one
// coalesced load, then __shfl-broadcast per edge -> one metadata load per
// 16 edges, and 16 independent 256B gathers in flight per group.
// Tail edges are padded with c=0,v=0: gather hits the hot row-0 line, FMA
// adds zero. No atomics, deterministic.
// ---------------------------------------------------------------------------
template <bool WRITE_NEXT>
__global__ __launch_bounds__(256) void k_spmm(const int* __restrict__ rowptr,
                       const int* __restrict__ cols,
                       const float* __restrict__ vals,
                       const float* __restrict__ x,
                       float* __restrict__ nxt,
                       float* __restrict__ acc) {
    const int wid   = (blockIdx.x * blockDim.x + threadIdx.x) >> 6;
    const int lane  = threadIdx.x & 63;
    const int l16   = lane & 15;
    const int gbase = lane & 48;           // 16-lane group base for shfl
    const int row   = wid * 4 + (lane >> 4);
    if (row >= NUM_NODES) return;          // group-uniform exit
    const int e0 = rowptr[row];
    const int e1 = rowptr[row + 1];
    const float4* __restrict__ x4 = (const float4*)x;
    float4 sum = make_float4(0.f, 0.f, 0.f, 0.f);
    for (int e = e0; e < e1; e += 16) {
        const int  idx = e + l16;
        const bool ok  = idx < e1;
        int   myc = ok ? cols[idx] : 0;
        float myv = ok ? vals[idx] : 0.f;
#pragma unroll
        for (int t = 0; t < 16; ++t) {
            int   c = __shfl(myc, gbase + t);
            float v = __shfl(myv, gbase + t);
            float4 xv = x4[(size_t)c * 16 + l16];   // 256B per 16-lane group
            sum.x += v * xv.x;  sum.y += v * xv.y;
            sum.z += v * xv.z;  sum.w += v * xv.w;
        }
    }
    const size_t o = (size_t)row * 16 + l16;
    if (WRITE_NEXT) ((float4*)nxt)[o] = sum;
    float4* acc4 = (float4*)acc;
    float4 a = acc4[o];
    a.x += sum.x; a.y += sum.y; a.z += sum.z; a.w += sum.w;
    acc4[o] = a;
}

// ---------------------------------------------------------------------------
// k_gamma: one wave per batch element; 64-lane dot + shuffle reduce; /16
// ---------------------------------------------------------------------------
__global__ void k_gamma(const float* __restrict__ acc,
                        const int* __restrict__ users,
                        const int* __restrict__ items,
                        float* __restrict__ out) {
    int wid  = (blockIdx.x * blockDim.x + threadIdx.x) >> 6;
    int lane = threadIdx.x & 63;
    if (wid >= BATCH) return;
    int u  = users[wid];
    int it = items[wid];
    float a = acc[(size_t)u * D + lane];
    float b = acc[((size_t)NUM_USERS + it) * D + lane];
    float p = a * b;
    for (int off = 32; off; off >>= 1) p += __shfl_down(p, off);
    if (lane == 0) out[wid] = p * (1.0f / 16.0f);
}

extern "C" void kernel_launch(void* const* d_in, const int* in_sizes, int n_in,
                              void* d_out, int out_size, void* d_ws, size_t ws_size,
                              hipStream_t stream) {
    const float* ue    = (const float*)d_in[0];
    const float* ie    = (const float*)d_in[1];
    const int*   rows  = (const int*)d_in[2];
    const int*   cols  = (const int*)d_in[3];
    const float* vals  = (const float*)d_in[4];
    const int*   users = (const int*)d_in[5];
    const int*   items = (const int*)d_in[6];
    float*       out   = (float*)d_out;

    // workspace layout: rowptr | bufA | bufB | acc
    char* ws = (char*)d_ws;
    size_t off = (((size_t)(NUM_NODES + 1) * sizeof(int)) + 255) & ~(size_t)255;
    int*   rowptr = (int*)ws;
    float* bufA   = (float*)(ws + off);
    float* bufB   = (float*)(ws + off + 1ull * NUM_NODES * D * sizeof(float));
    float* acc    = (float*)(ws + off + 2ull * NUM_NODES * D * sizeof(float));

    k_rowptr<<<(NUM_NODES + 1 + 255) / 256, 256, 0, stream>>>(rows, rowptr);
    k_init<<<2048, 256, 0, stream>>>(ue, ie, bufA, acc);

    // 3 SpMM layers; 4 rows per wave, 4 waves per block -> 16 rows/block
    const int spmm_blocks = NUM_NODES / 16;   // 150000/16 = 9375 exact
    k_spmm<true ><<<spmm_blocks, 256, 0, stream>>>(rowptr, cols, vals, bufA, bufB, acc);
    k_spmm<true ><<<spmm_blocks, 256, 0, stream>>>(rowptr, cols, vals, bufB, bufA, acc);
    k_spmm<false><<<spmm_blocks, 256, 0, stream>>>(rowptr, cols, vals, bufA, nullptr, acc);

    k_gamma<<<(BATCH * 64) / 256, 256, 0, stream>>>(acc, users, items, out);
}